// Round 1
// baseline (828.750 us; speedup 1.0000x reference)
//
#include <hip/hip_runtime.h>
#include <math.h>

#define N 16384
#define NWORDS 256       // N/64
#define FEAT 512
#define NUM_CATS 65
#define K 25
#define MAX_DETS 1000

// ---------------- ws layout (bytes) ----------------
// keys     : u64[N]            @ 0         (131072)
// rank     : u32[N]            @ 131072    (65536)
// sidx     : u32[N]            @ 196608    (65536)
// sbox     : float4[N]         @ 262144    (262144)
// sarea    : f32[N]            @ 524288    (65536)
// mask     : u64[N*NWORDS]     @ 589824    (33554432)
// idxArr   : i32[32]           @ 34144256  (128)   [31]=count
// keepOrig : u8[N]             @ 34144384  (16384)
// total ~34.2 MB

// Sort key: descending by score, ties -> ascending original index.
__global__ void k_build(const float* __restrict__ scores,
                        unsigned long long* __restrict__ keys,
                        unsigned int* __restrict__ rank) {
    int i = blockIdx.x * 256 + threadIdx.x;
    keys[i] = ((unsigned long long)__float_as_uint(scores[i]) << 32) |
              (unsigned long long)(0xFFFFFFFFu - (unsigned)i);
    rank[i] = 0u;
}

// rank[i] = #{ j : key[j] > key[i] }  (keys distinct -> permutation)
__global__ void k_rank(const unsigned long long* __restrict__ keys,
                       unsigned int* __restrict__ rank) {
    __shared__ unsigned long long lk[2048];
    int i = blockIdx.x * 256 + threadIdx.x;
    unsigned long long my = keys[i];
    int j0 = blockIdx.y * 2048;
    for (int t = threadIdx.x; t < 2048; t += 256) lk[t] = keys[j0 + t];
    __syncthreads();
    unsigned int cnt = 0;
#pragma unroll 8
    for (int t = 0; t < 2048; ++t) cnt += (lk[t] > my) ? 1u : 0u;
    atomicAdd(&rank[i], cnt);
}

__global__ void k_scatter(const unsigned int* __restrict__ rank,
                          unsigned int* __restrict__ sidx) {
    int i = blockIdx.x * 256 + threadIdx.x;
    sidx[rank[i]] = (unsigned int)i;
}

// Gather boxes into sorted order; precompute areas (exact ref formula).
__global__ void k_gather(const unsigned int* __restrict__ sidx,
                         const float* __restrict__ det_boxes,
                         float4* __restrict__ sbox,
                         float* __restrict__ sarea) {
    int p = blockIdx.x * 256 + threadIdx.x;
    unsigned o = sidx[p];
    float4 b = ((const float4*)det_boxes)[o];   // [y1,x1,y2,x2]
    sbox[p] = b;
    sarea[p] = (b.w - b.y) * (b.z - b.x);       // (x2-x1)*(y2-y1)
}

// Upper-triangular (block-wise) IoU>0.6 bit matrix. mask[row*256+cb] has
// bit j set iff IoU(row, cb*64+j) > 0.6 and col > row. Lower-tri words are
// never written and never read.
__global__ void k_mask(const float4* __restrict__ sbox,
                       const float* __restrict__ sarea,
                       unsigned long long* __restrict__ mask) {
    int cb = blockIdx.x, rb = blockIdx.y;
    if (cb < rb) return;
    __shared__ float4 cbox[64];
    __shared__ float carea[64];
    int t = threadIdx.x;
    int col0 = cb * 64;
    cbox[t] = sbox[col0 + t];
    carea[t] = sarea[col0 + t];
    __syncthreads();
    int row = rb * 64 + t;
    float4 r = sbox[row];
    float ra = sarea[row];
    unsigned long long bits = 0ull;
    for (int j = 0; j < 64; ++j) {
        int col = col0 + j;
        if (col > row) {
            float4 cbx = cbox[j];
            float iw = fminf(r.w, cbx.w) - fmaxf(r.y, cbx.y);  // x overlap
            iw = fmaxf(iw, 0.0f);
            float ih = fminf(r.z, cbx.z) - fmaxf(r.x, cbx.x);  // y overlap
            ih = fmaxf(ih, 0.0f);
            float inter = iw * ih;
            float iou = inter / (ra + carea[j] - inter + 1e-12f);
            if (iou > 0.6f) bits |= (1ull << j);
        }
    }
    mask[(size_t)row * NWORDS + cb] = bits;
}

// Serial greedy scan over 64-bit chunks. Wave 0 does the in-chunk serial
// greedy using the diagonal word held in registers (shfl broadcast); all
// 256 threads then OR the kept rows' mask words (1 word/thread) into the
// LDS suppressed bitmask. Early-exits (skips) once cnt reaches MAX_DETS.
__global__ void k_scan(const unsigned long long* __restrict__ mask,
                       const unsigned int* __restrict__ sidx,
                       unsigned char* __restrict__ keepOrig) {
    __shared__ unsigned long long supp[NWORDS];
    __shared__ unsigned long long keepw_arr[NWORDS];
    __shared__ int cntS;
    int tid = threadIdx.x;
    supp[tid] = 0ull;
    if (tid == 0) cntS = 0;
    __syncthreads();

    unsigned long long dnext = 0ull;
    if (tid < 64) dnext = mask[(size_t)tid * NWORDS];   // diag words, chunk 0

    for (int c = 0; c < NWORDS; ++c) {
        int curcnt = cntS;                 // uniform (read after barrier)
        if (curcnt >= MAX_DETS) {          // nothing further is kept/suppressed
            if (tid == 0) keepw_arr[c] = 0ull;
            continue;
        }
        unsigned long long dcur = dnext;
        if (tid < 64 && c + 1 < NWORDS)    // prefetch next chunk's diagonal
            dnext = mask[(size_t)((c + 1) * 64 + tid) * NWORDS + (c + 1)];

        if (tid < 64) {
            unsigned long long alive = ~supp[c];
            unsigned long long keepw = 0ull;
            int cnt = curcnt;
            for (int t = 0; t < 64; ++t) {
                if (cnt < MAX_DETS && ((alive >> t) & 1ull)) {
                    keepw |= (1ull << t);
                    ++cnt;
                    unsigned long long dt = __shfl(dcur, t, 64); // uniform
                    alive &= ~dt;
                }
            }
            if (tid == 0) { keepw_arr[c] = keepw; cntS = cnt; }
        }
        __syncthreads();

        unsigned long long kw = keepw_arr[c];
        if (tid >= c && kw) {
            unsigned long long s = supp[tid];
            unsigned long long w = kw;
            while (w) {
                int t = __ffsll((long long)w) - 1;
                w &= (w - 1ull);
                s |= mask[(size_t)(c * 64 + t) * NWORDS + tid];
            }
            supp[tid] = s;
        }
        __syncthreads();
    }
    __syncthreads();
    for (int i = tid; i < N; i += 256) {
        unsigned char b = (unsigned char)((keepw_arr[i >> 6] >> (i & 63)) & 1ull);
        keepOrig[sidx[i]] = b;
    }
}

// valid = keep & ~all(roi_boxes==0) & (score>=0.9) & (rescaled area>220);
// collect first K valid in original-index order + total count.
__global__ void k_select(const unsigned char* __restrict__ keepOrig,
                         const float* __restrict__ roi_boxes,
                         const float* __restrict__ roi_scores,
                         const float* __restrict__ det_boxes,
                         const float* __restrict__ info,
                         int* __restrict__ idxArr) {
    __shared__ int wcnt[16];
    int tid = threadIdx.x;
    if (tid < K) idxArr[tid] = 0;
    __syncthreads();
    float sy = info[4], sx = info[5];
    int base = 0;
    for (int ch = 0; ch < 16; ++ch) {
        int i = ch * 1024 + tid;
        bool keep = keepOrig[i] != 0;
        float4 rb = ((const float4*)roi_boxes)[i];
        bool nz = !((rb.x == 0.0f) && (rb.y == 0.0f) && (rb.z == 0.0f) && (rb.w == 0.0f));
        bool sc = roi_scores[i] >= 0.9f;
        float4 db = ((const float4*)det_boxes)[i];
        float r0 = db.x / sy, r1 = db.y / sx, r2 = db.z / sy, r3 = db.w / sx;
        bool big = ((r2 - r0) * (r3 - r1)) > 220.0f;
        bool valid = keep && nz && sc && big;
        unsigned long long bal = __ballot(valid);
        int wv = tid >> 6, lane = tid & 63;
        if (lane == 0) wcnt[wv] = (int)__popcll(bal);
        __syncthreads();
        int pre = 0, tot = 0;
        for (int w = 0; w < 16; ++w) { int cc = wcnt[w]; tot += cc; if (w < wv) pre += cc; }
        int rk = base + pre + (int)__popcll(bal & ((1ull << lane) - 1ull));
        if (valid && rk < K) idxArr[rk] = i;
        base += tot;
        __syncthreads();
    }
    if (tid == 0) idxArr[31] = base;   // full valid count
}

// 25x65 classification, argmax/fg, stable descending sort, epilogue writes.
__global__ void k_classify(const float* __restrict__ vis,
                           const float* __restrict__ tf,
                           const float* __restrict__ det_boxes,
                           const float* __restrict__ info,
                           const int* __restrict__ idxArr,
                           float* __restrict__ out) {
    __shared__ float feat[K * FEAT];       // 51200 B
    __shared__ float sc[K * NUM_CATS];     // 6500 B
    __shared__ float keyL[K];
    __shared__ int fgL[K];
    __shared__ int ordL[K];
    int tid = threadIdx.x;
    int count = idxArr[31];
    int mincount = count < K ? count : K;

    for (int r = 0; r < K; ++r) {
        int o = idxArr[r];
        for (int e = tid; e < FEAT; e += 256)
            feat[r * FEAT + e] = vis[(size_t)o * FEAT + e];
    }
    __syncthreads();

    for (int p = tid; p < K * NUM_CATS; p += 256) {
        int r = p / NUM_CATS, c = p % NUM_CATS;
        const float* fr = &feat[r * FEAT];
        const float* tr = &tf[(size_t)c * FEAT];
        float s = 0.0f;
#pragma unroll 8
        for (int e = 0; e < FEAT; ++e) s += fr[e] * tr[e];
        sc[p] = s;
    }
    __syncthreads();

    if (tid < K) {
        float mv = sc[tid * NUM_CATS];
        int ma = 0;
        for (int c = 1; c < NUM_CATS; ++c) {
            float v = sc[tid * NUM_CATS + c];
            if (v > mv) { mv = v; ma = c; }     // first-max (jnp.argmax)
        }
        int fg = (tid < mincount) && (ma != 0);
        fgL[tid] = fg;
        keyL[tid] = fg ? mv : -INFINITY;
    }
    __syncthreads();

    if (tid == 0) {                 // stable selection sort, descending
        unsigned used = 0;
        for (int p = 0; p < K; ++p) {
            int bk = -1; float bv = 0.0f;
            for (int k2 = 0; k2 < K; ++k2) {
                if (used & (1u << k2)) continue;
                if (bk < 0 || keyL[k2] > bv) { bk = k2; bv = keyL[k2]; }
            }
            ordL[p] = bk;
            used |= (1u << bk);
        }
    }
    __syncthreads();

    float sy = info[4], sx = info[5];
    // scores: [0 .. 1599]
    for (int p = tid; p < K * (NUM_CATS - 1); p += 256) {
        int q = p >> 6, cc = p & 63;
        int src = ordL[q];
        out[p] = fgL[src] ? sc[src * NUM_CATS + cc + 1] : 0.0f;
    }
    // bboxes: [1600 .. 1699]  processed = [xmin, ymin, xmax, ymax]
    for (int p = tid; p < K * 4; p += 256) {
        int q = p >> 2, e = p & 3;
        int src = ordL[q];
        float v = 0.0f;
        if (fgL[src]) {
            int o = idxArr[src];
            float b0 = det_boxes[o * 4 + 0] / sy;   // ymin
            float b1 = det_boxes[o * 4 + 1] / sx;   // xmin
            float b2 = det_boxes[o * 4 + 2] / sy;   // ymax
            float b3 = det_boxes[o * 4 + 3] / sx;   // xmax
            v = (e == 0) ? b1 : (e == 1) ? b0 : (e == 2) ? b3 : b2;
        }
        out[1600 + p] = v;
    }
    // mask: [1700 .. 1724]
    if (tid < K) out[1700 + tid] = fgL[ordL[tid]] ? 1.0f : 0.0f;
}

extern "C" void kernel_launch(void* const* d_in, const int* in_sizes, int n_in,
                              void* d_out, int out_size, void* d_ws, size_t ws_size,
                              hipStream_t stream) {
    const float* roi_boxes  = (const float*)d_in[0];
    const float* roi_scores = (const float*)d_in[1];
    const float* det_boxes  = (const float*)d_in[2];
    // d_in[3] detection_masks: unused by reference
    const float* vis        = (const float*)d_in[4];
    const float* info       = (const float*)d_in[5];
    const float* tf         = (const float*)d_in[6];

    char* ws = (char*)d_ws;
    unsigned long long* keys = (unsigned long long*)(ws + 0);
    unsigned int* rank       = (unsigned int*)(ws + 131072);
    unsigned int* sidx       = (unsigned int*)(ws + 196608);
    float4* sbox             = (float4*)(ws + 262144);
    float* sarea             = (float*)(ws + 524288);
    unsigned long long* mask = (unsigned long long*)(ws + 589824);
    int* idxArr              = (int*)(ws + 34144256);
    unsigned char* keepOrig  = (unsigned char*)(ws + 34144384);

    k_build<<<64, 256, 0, stream>>>(roi_scores, keys, rank);
    k_rank<<<dim3(64, 8), 256, 0, stream>>>(keys, rank);
    k_scatter<<<64, 256, 0, stream>>>(rank, sidx);
    k_gather<<<64, 256, 0, stream>>>(sidx, det_boxes, sbox, sarea);
    k_mask<<<dim3(NWORDS, NWORDS), 64, 0, stream>>>(sbox, sarea, mask);
    k_scan<<<1, 256, 0, stream>>>(mask, sidx, keepOrig);
    k_select<<<1, 1024, 0, stream>>>(keepOrig, roi_boxes, roi_scores, det_boxes, info, idxArr);
    k_classify<<<1, 256, 0, stream>>>(vis, tf, det_boxes, info, idxArr, (float*)d_out);
}

// Round 2
// 774.732 us; speedup vs baseline: 1.0697x; 1.0697x over previous
//
#include <hip/hip_runtime.h>
#include <math.h>

#define N 16384
#define NWORDS 256       // N/64
#define FEAT 512
#define NUM_CATS 65
#define K 25
#define MAX_DETS 1000

// ---------------- ws layout (bytes) ----------------
// keys     : u64[N]            @ 0         (131072)
// rank     : u32[N]            @ 131072    (65536)
// sidx     : u32[N]            @ 196608    (65536)
// sbox     : float4[N]         @ 262144    (262144)
// sarea    : f32[N]            @ 524288    (65536)
// mask     : u64[N*NWORDS]     @ 589824    (33554432)
// idxArr   : i32[32]           @ 34144256  (128)   [31]=count
// keepOrig : u8[N]             @ 34144384  (16384)
// total ~34.2 MB

// Sort key: descending by score, ties -> ascending original index.
__global__ void k_build(const float* __restrict__ scores,
                        unsigned long long* __restrict__ keys,
                        unsigned int* __restrict__ rank) {
    int i = blockIdx.x * 256 + threadIdx.x;
    keys[i] = ((unsigned long long)__float_as_uint(scores[i]) << 32) |
              (unsigned long long)(0xFFFFFFFFu - (unsigned)i);
    rank[i] = 0u;
}

// rank[i] = #{ j : key[j] > key[i] }  (keys distinct -> permutation)
__global__ void k_rank(const unsigned long long* __restrict__ keys,
                       unsigned int* __restrict__ rank) {
    __shared__ unsigned long long lk[2048];
    int i = blockIdx.x * 256 + threadIdx.x;
    unsigned long long my = keys[i];
    int j0 = blockIdx.y * 2048;
    for (int t = threadIdx.x; t < 2048; t += 256) lk[t] = keys[j0 + t];
    __syncthreads();
    unsigned int cnt = 0;
#pragma unroll 8
    for (int t = 0; t < 2048; ++t) cnt += (lk[t] > my) ? 1u : 0u;
    atomicAdd(&rank[i], cnt);
}

__global__ void k_scatter(const unsigned int* __restrict__ rank,
                          unsigned int* __restrict__ sidx) {
    int i = blockIdx.x * 256 + threadIdx.x;
    sidx[rank[i]] = (unsigned int)i;
}

// Gather boxes into sorted order; precompute areas (exact ref formula).
__global__ void k_gather(const unsigned int* __restrict__ sidx,
                         const float* __restrict__ det_boxes,
                         float4* __restrict__ sbox,
                         float* __restrict__ sarea) {
    int p = blockIdx.x * 256 + threadIdx.x;
    unsigned o = sidx[p];
    float4 b = ((const float4*)det_boxes)[o];   // [y1,x1,y2,x2]
    sbox[p] = b;
    sarea[p] = (b.w - b.y) * (b.z - b.x);       // (x2-x1)*(y2-y1)
}

// Upper-triangular (block-wise) IoU>0.6 bit matrix. mask[row*256+cb] has
// bit j set iff IoU(row, cb*64+j) > 0.6 and col > row. Lower-tri words are
// never written (garbage) and never read in a way that matters.
__global__ void k_mask(const float4* __restrict__ sbox,
                       const float* __restrict__ sarea,
                       unsigned long long* __restrict__ mask) {
    int cb = blockIdx.x, rb = blockIdx.y;
    if (cb < rb) return;
    __shared__ float4 cbox[64];
    __shared__ float carea[64];
    int t = threadIdx.x;
    int col0 = cb * 64;
    cbox[t] = sbox[col0 + t];
    carea[t] = sarea[col0 + t];
    __syncthreads();
    int row = rb * 64 + t;
    float4 r = sbox[row];
    float ra = sarea[row];
    unsigned long long bits = 0ull;
    for (int j = 0; j < 64; ++j) {
        int col = col0 + j;
        if (col > row) {
            float4 cbx = cbox[j];
            float iw = fminf(r.w, cbx.w) - fmaxf(r.y, cbx.y);  // x overlap
            iw = fmaxf(iw, 0.0f);
            float ih = fminf(r.z, cbx.z) - fmaxf(r.x, cbx.x);  // y overlap
            ih = fmaxf(ih, 0.0f);
            float inter = iw * ih;
            float iou = inter / (ra + carea[j] - inter + 1e-12f);
            if (iou > 0.6f) bits |= (1ull << j);
        }
    }
    mask[(size_t)row * NWORDS + cb] = bits;
}

// Single-wave, barrier-free greedy scan. The 256-word suppressed bitmask
// lives in registers: lane (W>>2) owns word W in reg (W&3). Per chunk:
// one shfl broadcast of the supp word, then an ffs-driven loop over alive
// bits (every alive bit IS a kept box), each kept row OR'd into supp via
// two coalesced dwordx4 loads per lane (2 KB/row). Hard break at MAX_DETS.
__global__ void __launch_bounds__(64, 1)
k_scan(const unsigned long long* __restrict__ mask,
       const unsigned int* __restrict__ sidx,
       unsigned char* __restrict__ keepOrig) {
    __shared__ unsigned long long keepw_arr[NWORDS];
    int lane = threadIdx.x;                       // 64 threads = 1 wave
    unsigned long long s0 = 0, s1 = 0, s2 = 0, s3 = 0;  // supp words lane*4+0..3
    int cnt = 0;                                  // uniform across lanes

    // prefetch chunk 0's diagonal word (row lane, col-chunk 0)
    unsigned long long dnext = mask[(size_t)lane * NWORDS];

    for (int c = 0; c < NWORDS; ++c) {
        if (cnt >= MAX_DETS) {                    // nothing further kept/suppressed
            for (int cc = c + lane; cc < NWORDS; cc += 64) keepw_arr[cc] = 0ull;
            break;
        }
        unsigned long long dcur = dnext;
        if (c + 1 < NWORDS)                       // prefetch next diagonal
            dnext = mask[(size_t)((c + 1) * 64 + lane) * NWORDS + (c + 1)];

        // broadcast supp word c from its owner lane/reg
        unsigned long long sw;
        switch (c & 3) {
            case 0: sw = s0; break;
            case 1: sw = s1; break;
            case 2: sw = s2; break;
            default: sw = s3; break;
        }
        sw = __shfl(sw, c >> 2, 64);
        unsigned long long alive = ~sw;           // uniform on all lanes

        unsigned long long keepw = 0ull;
        while (alive && cnt < MAX_DETS) {
            int t = __ffsll((long long)alive) - 1;   // lowest alive bit -> kept
            keepw |= (1ull << t);
            ++cnt;
            unsigned long long dt = __shfl(dcur, t, 64);  // in-chunk suppression
            alive &= ~(dt | (1ull << t));
            // apply kept row to all future supp words (coalesced 32B/lane).
            // Words <= c are lower-tri garbage but never read again.
            const unsigned long long* rowp = mask + (size_t)(c * 64 + t) * NWORDS + lane * 4;
            s0 |= rowp[0];
            s1 |= rowp[1];
            s2 |= rowp[2];
            s3 |= rowp[3];
        }
        if (lane == 0) keepw_arr[c] = keepw;
    }

    // scatter keep bits back to original index order
    for (int i = lane; i < N; i += 64) {
        unsigned char b = (unsigned char)((keepw_arr[i >> 6] >> (i & 63)) & 1ull);
        keepOrig[sidx[i]] = b;
    }
}

// valid = keep & ~all(roi_boxes==0) & (score>=0.9) & (rescaled area>220);
// collect first K valid in original-index order + total count.
__global__ void k_select(const unsigned char* __restrict__ keepOrig,
                         const float* __restrict__ roi_boxes,
                         const float* __restrict__ roi_scores,
                         const float* __restrict__ det_boxes,
                         const float* __restrict__ info,
                         int* __restrict__ idxArr) {
    __shared__ int wcnt[16];
    int tid = threadIdx.x;
    if (tid < K) idxArr[tid] = 0;
    __syncthreads();
    float sy = info[4], sx = info[5];
    int base = 0;
    for (int ch = 0; ch < 16; ++ch) {
        int i = ch * 1024 + tid;
        bool keep = keepOrig[i] != 0;
        float4 rb = ((const float4*)roi_boxes)[i];
        bool nz = !((rb.x == 0.0f) && (rb.y == 0.0f) && (rb.z == 0.0f) && (rb.w == 0.0f));
        bool sc = roi_scores[i] >= 0.9f;
        float4 db = ((const float4*)det_boxes)[i];
        float r0 = db.x / sy, r1 = db.y / sx, r2 = db.z / sy, r3 = db.w / sx;
        bool big = ((r2 - r0) * (r3 - r1)) > 220.0f;
        bool valid = keep && nz && sc && big;
        unsigned long long bal = __ballot(valid);
        int wv = tid >> 6, lane = tid & 63;
        if (lane == 0) wcnt[wv] = (int)__popcll(bal);
        __syncthreads();
        int pre = 0, tot = 0;
        for (int w = 0; w < 16; ++w) { int cc = wcnt[w]; tot += cc; if (w < wv) pre += cc; }
        int rk = base + pre + (int)__popcll(bal & ((1ull << lane) - 1ull));
        if (valid && rk < K) idxArr[rk] = i;
        base += tot;
        __syncthreads();
    }
    if (tid == 0) idxArr[31] = base;   // full valid count
}

// 25x65 classification, argmax/fg, stable descending sort, epilogue writes.
__global__ void k_classify(const float* __restrict__ vis,
                           const float* __restrict__ tf,
                           const float* __restrict__ det_boxes,
                           const float* __restrict__ info,
                           const int* __restrict__ idxArr,
                           float* __restrict__ out) {
    __shared__ float feat[K * FEAT];       // 51200 B
    __shared__ float sc[K * NUM_CATS];     // 6500 B
    __shared__ float keyL[K];
    __shared__ int fgL[K];
    __shared__ int ordL[K];
    int tid = threadIdx.x;
    int count = idxArr[31];
    int mincount = count < K ? count : K;

    for (int r = 0; r < K; ++r) {
        int o = idxArr[r];
        for (int e = tid; e < FEAT; e += 256)
            feat[r * FEAT + e] = vis[(size_t)o * FEAT + e];
    }
    __syncthreads();

    for (int p = tid; p < K * NUM_CATS; p += 256) {
        int r = p / NUM_CATS, c = p % NUM_CATS;
        const float* fr = &feat[r * FEAT];
        const float* tr = &tf[(size_t)c * FEAT];
        float s = 0.0f;
#pragma unroll 8
        for (int e = 0; e < FEAT; ++e) s += fr[e] * tr[e];
        sc[p] = s;
    }
    __syncthreads();

    if (tid < K) {
        float mv = sc[tid * NUM_CATS];
        int ma = 0;
        for (int c = 1; c < NUM_CATS; ++c) {
            float v = sc[tid * NUM_CATS + c];
            if (v > mv) { mv = v; ma = c; }     // first-max (jnp.argmax)
        }
        int fg = (tid < mincount) && (ma != 0);
        fgL[tid] = fg;
        keyL[tid] = fg ? mv : -INFINITY;
    }
    __syncthreads();

    if (tid == 0) {                 // stable selection sort, descending
        unsigned used = 0;
        for (int p = 0; p < K; ++p) {
            int bk = -1; float bv = 0.0f;
            for (int k2 = 0; k2 < K; ++k2) {
                if (used & (1u << k2)) continue;
                if (bk < 0 || keyL[k2] > bv) { bk = k2; bv = keyL[k2]; }
            }
            ordL[p] = bk;
            used |= (1u << bk);
        }
    }
    __syncthreads();

    float sy = info[4], sx = info[5];
    // scores: [0 .. 1599]
    for (int p = tid; p < K * (NUM_CATS - 1); p += 256) {
        int q = p >> 6, cc = p & 63;
        int src = ordL[q];
        out[p] = fgL[src] ? sc[src * NUM_CATS + cc + 1] : 0.0f;
    }
    // bboxes: [1600 .. 1699]  processed = [xmin, ymin, xmax, ymax]
    for (int p = tid; p < K * 4; p += 256) {
        int q = p >> 2, e = p & 3;
        int src = ordL[q];
        float v = 0.0f;
        if (fgL[src]) {
            int o = idxArr[src];
            float b0 = det_boxes[o * 4 + 0] / sy;   // ymin
            float b1 = det_boxes[o * 4 + 1] / sx;   // xmin
            float b2 = det_boxes[o * 4 + 2] / sy;   // ymax
            float b3 = det_boxes[o * 4 + 3] / sx;   // xmax
            v = (e == 0) ? b1 : (e == 1) ? b0 : (e == 2) ? b3 : b2;
        }
        out[1600 + p] = v;
    }
    // mask: [1700 .. 1724]
    if (tid < K) out[1700 + tid] = fgL[ordL[tid]] ? 1.0f : 0.0f;
}

extern "C" void kernel_launch(void* const* d_in, const int* in_sizes, int n_in,
                              void* d_out, int out_size, void* d_ws, size_t ws_size,
                              hipStream_t stream) {
    const float* roi_boxes  = (const float*)d_in[0];
    const float* roi_scores = (const float*)d_in[1];
    const float* det_boxes  = (const float*)d_in[2];
    // d_in[3] detection_masks: unused by reference
    const float* vis        = (const float*)d_in[4];
    const float* info       = (const float*)d_in[5];
    const float* tf         = (const float*)d_in[6];

    char* ws = (char*)d_ws;
    unsigned long long* keys = (unsigned long long*)(ws + 0);
    unsigned int* rank       = (unsigned int*)(ws + 131072);
    unsigned int* sidx       = (unsigned int*)(ws + 196608);
    float4* sbox             = (float4*)(ws + 262144);
    float* sarea             = (float*)(ws + 524288);
    unsigned long long* mask = (unsigned long long*)(ws + 589824);
    int* idxArr              = (int*)(ws + 34144256);
    unsigned char* keepOrig  = (unsigned char*)(ws + 34144384);

    k_build<<<64, 256, 0, stream>>>(roi_scores, keys, rank);
    k_rank<<<dim3(64, 8), 256, 0, stream>>>(keys, rank);
    k_scatter<<<64, 256, 0, stream>>>(rank, sidx);
    k_gather<<<64, 256, 0, stream>>>(sidx, det_boxes, sbox, sarea);
    k_mask<<<dim3(NWORDS, NWORDS), 64, 0, stream>>>(sbox, sarea, mask);
    k_scan<<<1, 64, 0, stream>>>(mask, sidx, keepOrig);
    k_select<<<1, 1024, 0, stream>>>(keepOrig, roi_boxes, roi_scores, det_boxes, info, idxArr);
    k_classify<<<1, 256, 0, stream>>>(vis, tf, det_boxes, info, idxArr, (float*)d_out);
}

// Round 3
// 658.226 us; speedup vs baseline: 1.2591x; 1.1770x over previous
//
#include <hip/hip_runtime.h>
#include <math.h>

#define N 16384
#define NWORDS 256       // N/64
#define FEAT 512
#define NUM_CATS 65
#define K 25
#define MAX_DETS 1000

// ---------------- ws layout (bytes) ----------------
// keys     : u64[N]            @ 0         (131072)
// rank     : u32[N]            @ 131072    (65536)
// sidx     : u32[N]            @ 196608    (65536)
// sbox     : float4[N]         @ 262144    (262144)
// sarea    : f32[N]            @ 524288    (65536)
// mask     : u64[N*NWORDS]     @ 589824    (33554432)
// idxArr   : i32[32]           @ 34144256  (128)   [31]=count
// keepOrig : u8[N]             @ 34144384  (16384)
// total ~34.2 MB

// Sort key: descending by score, ties -> ascending original index.
__global__ void k_build(const float* __restrict__ scores,
                        unsigned long long* __restrict__ keys,
                        unsigned int* __restrict__ rank) {
    int i = blockIdx.x * 256 + threadIdx.x;
    keys[i] = ((unsigned long long)__float_as_uint(scores[i]) << 32) |
              (unsigned long long)(0xFFFFFFFFu - (unsigned)i);
    rank[i] = 0u;
}

// rank[i] = #{ j : key[j] > key[i] }  (keys distinct -> permutation)
__global__ void k_rank(const unsigned long long* __restrict__ keys,
                       unsigned int* __restrict__ rank) {
    __shared__ unsigned long long lk[2048];
    int i = blockIdx.x * 256 + threadIdx.x;
    unsigned long long my = keys[i];
    int j0 = blockIdx.y * 2048;
    for (int t = threadIdx.x; t < 2048; t += 256) lk[t] = keys[j0 + t];
    __syncthreads();
    unsigned int cnt = 0;
#pragma unroll 8
    for (int t = 0; t < 2048; ++t) cnt += (lk[t] > my) ? 1u : 0u;
    atomicAdd(&rank[i], cnt);
}

__global__ void k_scatter(const unsigned int* __restrict__ rank,
                          unsigned int* __restrict__ sidx) {
    int i = blockIdx.x * 256 + threadIdx.x;
    sidx[rank[i]] = (unsigned int)i;
}

// Gather boxes into sorted order; precompute areas (exact ref formula).
__global__ void k_gather(const unsigned int* __restrict__ sidx,
                         const float* __restrict__ det_boxes,
                         float4* __restrict__ sbox,
                         float* __restrict__ sarea) {
    int p = blockIdx.x * 256 + threadIdx.x;
    unsigned o = sidx[p];
    float4 b = ((const float4*)det_boxes)[o];   // [y1,x1,y2,x2]
    sbox[p] = b;
    sarea[p] = (b.w - b.y) * (b.z - b.x);       // (x2-x1)*(y2-y1)
}

// Upper-triangular (block-wise) IoU>0.6 bit matrix. mask[row*256+cb] has
// bit j set iff IoU(row, cb*64+j) > 0.6 and col > row. Lower-tri words are
// never written (garbage) and never read in a way that matters.
__global__ void k_mask(const float4* __restrict__ sbox,
                       const float* __restrict__ sarea,
                       unsigned long long* __restrict__ mask) {
    int cb = blockIdx.x, rb = blockIdx.y;
    if (cb < rb) return;
    __shared__ float4 cbox[64];
    __shared__ float carea[64];
    int t = threadIdx.x;
    int col0 = cb * 64;
    cbox[t] = sbox[col0 + t];
    carea[t] = sarea[col0 + t];
    __syncthreads();
    int row = rb * 64 + t;
    float4 r = sbox[row];
    float ra = sarea[row];
    unsigned long long bits = 0ull;
    for (int j = 0; j < 64; ++j) {
        int col = col0 + j;
        if (col > row) {
            float4 cbx = cbox[j];
            float iw = fminf(r.w, cbx.w) - fmaxf(r.y, cbx.y);  // x overlap
            iw = fmaxf(iw, 0.0f);
            float ih = fminf(r.z, cbx.z) - fmaxf(r.x, cbx.x);  // y overlap
            ih = fmaxf(ih, 0.0f);
            float inter = iw * ih;
            float iou = inter / (ra + carea[j] - inter + 1e-12f);
            if (iou > 0.6f) bits |= (1ull << j);
        }
    }
    mask[(size_t)row * NWORDS + cb] = bits;
}

// Single-wave, barrier-free greedy scan. supp bitmask in registers:
// lane (W>>2) owns word W in reg (W&3). Per chunk: phase A decides keeps
// using only registers (dcur shfl); phase B ORs kept rows into supp in
// groups of 8 with 8 independent accumulator quads so all 16 dwordx4
// loads of a group are in flight before any OR consumes them (one memory
// latency per 8 kept rows instead of per row).
__global__ void __launch_bounds__(64, 1)
k_scan(const unsigned long long* __restrict__ mask,
       const unsigned int* __restrict__ sidx,
       unsigned char* __restrict__ keepOrig) {
    __shared__ unsigned long long keepw_arr[NWORDS];
    int lane = threadIdx.x;                       // 64 threads = 1 wave
    unsigned long long s0 = 0, s1 = 0, s2 = 0, s3 = 0;  // supp words lane*4+0..3
    int cnt = 0;                                  // uniform across lanes

    // prefetch chunk 0's diagonal word (row lane, col-chunk 0)
    unsigned long long dnext = mask[(size_t)lane * NWORDS];

    for (int c = 0; c < NWORDS; ++c) {
        if (cnt >= MAX_DETS) {                    // nothing further kept/suppressed
            for (int cc = c + lane; cc < NWORDS; cc += 64) keepw_arr[cc] = 0ull;
            break;
        }
        unsigned long long dcur = dnext;
        if (c + 1 < NWORDS)                       // prefetch next diagonal
            dnext = mask[(size_t)((c + 1) * 64 + lane) * NWORDS + (c + 1)];

        // broadcast supp word c from its owner lane/reg
        unsigned long long sw;
        switch (c & 3) {
            case 0: sw = s0; break;
            case 1: sw = s1; break;
            case 2: sw = s2; break;
            default: sw = s3; break;
        }
        sw = __shfl(sw, c >> 2, 64);
        unsigned long long alive = ~sw;           // uniform on all lanes

        // ---- phase A: greedy keep decisions, registers only ----
        unsigned long long keepw = 0ull;
        while (alive && cnt < MAX_DETS) {
            int t = __ffsll((long long)alive) - 1;   // lowest alive bit -> kept
            keepw |= (1ull << t);
            ++cnt;
            unsigned long long dt = __shfl(dcur, t, 64);  // in-chunk suppression
            alive &= ~(dt | (1ull << t));
        }
        if (lane == 0) keepw_arr[c] = keepw;

        // ---- phase B: batched suppression OR (skip if we just hit the cap) ----
        if (cnt < MAX_DETS) {
            const unsigned long long* mbase =
                mask + (size_t)(c * 64) * NWORDS + lane * 4;
            unsigned long long w = keepw;
            while (w) {
#define SLOT(i)                                                               \
                unsigned long long A##i##0 = 0, A##i##1 = 0,                  \
                                   A##i##2 = 0, A##i##3 = 0;                  \
                if (w) {                                                      \
                    int t = __ffsll((long long)w) - 1;                        \
                    w &= w - 1ull;                                            \
                    const unsigned long long* p = mbase + (size_t)t * NWORDS; \
                    A##i##0 = p[0]; A##i##1 = p[1];                           \
                    A##i##2 = p[2]; A##i##3 = p[3];                           \
                }
                SLOT(0) SLOT(1) SLOT(2) SLOT(3) SLOT(4) SLOT(5) SLOT(6) SLOT(7)
#undef SLOT
                s0 |= A00 | A10 | A20 | A30 | A40 | A50 | A60 | A70;
                s1 |= A01 | A11 | A21 | A31 | A41 | A51 | A61 | A71;
                s2 |= A02 | A12 | A22 | A32 | A42 | A52 | A62 | A72;
                s3 |= A03 | A13 | A23 | A33 | A43 | A53 | A63 | A73;
            }
        }
    }

    // scatter keep bits back to original index order
    for (int i = lane; i < N; i += 64) {
        unsigned char b = (unsigned char)((keepw_arr[i >> 6] >> (i & 63)) & 1ull);
        keepOrig[sidx[i]] = b;
    }
}

// valid = keep & ~all(roi_boxes==0) & (score>=0.9) & (rescaled area>220);
// collect first K valid in original-index order + total count.
__global__ void k_select(const unsigned char* __restrict__ keepOrig,
                         const float* __restrict__ roi_boxes,
                         const float* __restrict__ roi_scores,
                         const float* __restrict__ det_boxes,
                         const float* __restrict__ info,
                         int* __restrict__ idxArr) {
    __shared__ int wcnt[16];
    int tid = threadIdx.x;
    if (tid < K) idxArr[tid] = 0;
    __syncthreads();
    float sy = info[4], sx = info[5];
    int base = 0;
    for (int ch = 0; ch < 16; ++ch) {
        int i = ch * 1024 + tid;
        bool keep = keepOrig[i] != 0;
        float4 rb = ((const float4*)roi_boxes)[i];
        bool nz = !((rb.x == 0.0f) && (rb.y == 0.0f) && (rb.z == 0.0f) && (rb.w == 0.0f));
        bool sc = roi_scores[i] >= 0.9f;
        float4 db = ((const float4*)det_boxes)[i];
        float r0 = db.x / sy, r1 = db.y / sx, r2 = db.z / sy, r3 = db.w / sx;
        bool big = ((r2 - r0) * (r3 - r1)) > 220.0f;
        bool valid = keep && nz && sc && big;
        unsigned long long bal = __ballot(valid);
        int wv = tid >> 6, lane = tid & 63;
        if (lane == 0) wcnt[wv] = (int)__popcll(bal);
        __syncthreads();
        int pre = 0, tot = 0;
        for (int w = 0; w < 16; ++w) { int cc = wcnt[w]; tot += cc; if (w < wv) pre += cc; }
        int rk = base + pre + (int)__popcll(bal & ((1ull << lane) - 1ull));
        if (valid && rk < K) idxArr[rk] = i;
        base += tot;
        __syncthreads();
    }
    if (tid == 0) idxArr[31] = base;   // full valid count
}

// 25x65 classification, argmax/fg, stable descending sort, epilogue writes.
__global__ void k_classify(const float* __restrict__ vis,
                           const float* __restrict__ tf,
                           const float* __restrict__ det_boxes,
                           const float* __restrict__ info,
                           const int* __restrict__ idxArr,
                           float* __restrict__ out) {
    __shared__ float feat[K * FEAT];       // 51200 B
    __shared__ float sc[K * NUM_CATS];     // 6500 B
    __shared__ float keyL[K];
    __shared__ int fgL[K];
    __shared__ int ordL[K];
    int tid = threadIdx.x;
    int count = idxArr[31];
    int mincount = count < K ? count : K;

    for (int r = 0; r < K; ++r) {
        int o = idxArr[r];
        for (int e = tid; e < FEAT; e += 256)
            feat[r * FEAT + e] = vis[(size_t)o * FEAT + e];
    }
    __syncthreads();

    for (int p = tid; p < K * NUM_CATS; p += 256) {
        int r = p / NUM_CATS, c = p % NUM_CATS;
        const float* fr = &feat[r * FEAT];
        const float* tr = &tf[(size_t)c * FEAT];
        float s = 0.0f;
#pragma unroll 8
        for (int e = 0; e < FEAT; ++e) s += fr[e] * tr[e];
        sc[p] = s;
    }
    __syncthreads();

    if (tid < K) {
        float mv = sc[tid * NUM_CATS];
        int ma = 0;
        for (int c = 1; c < NUM_CATS; ++c) {
            float v = sc[tid * NUM_CATS + c];
            if (v > mv) { mv = v; ma = c; }     // first-max (jnp.argmax)
        }
        int fg = (tid < mincount) && (ma != 0);
        fgL[tid] = fg;
        keyL[tid] = fg ? mv : -INFINITY;
    }
    __syncthreads();

    if (tid == 0) {                 // stable selection sort, descending
        unsigned used = 0;
        for (int p = 0; p < K; ++p) {
            int bk = -1; float bv = 0.0f;
            for (int k2 = 0; k2 < K; ++k2) {
                if (used & (1u << k2)) continue;
                if (bk < 0 || keyL[k2] > bv) { bk = k2; bv = keyL[k2]; }
            }
            ordL[p] = bk;
            used |= (1u << bk);
        }
    }
    __syncthreads();

    float sy = info[4], sx = info[5];
    // scores: [0 .. 1599]
    for (int p = tid; p < K * (NUM_CATS - 1); p += 256) {
        int q = p >> 6, cc = p & 63;
        int src = ordL[q];
        out[p] = fgL[src] ? sc[src * NUM_CATS + cc + 1] : 0.0f;
    }
    // bboxes: [1600 .. 1699]  processed = [xmin, ymin, xmax, ymax]
    for (int p = tid; p < K * 4; p += 256) {
        int q = p >> 2, e = p & 3;
        int src = ordL[q];
        float v = 0.0f;
        if (fgL[src]) {
            int o = idxArr[src];
            float b0 = det_boxes[o * 4 + 0] / sy;   // ymin
            float b1 = det_boxes[o * 4 + 1] / sx;   // xmin
            float b2 = det_boxes[o * 4 + 2] / sy;   // ymax
            float b3 = det_boxes[o * 4 + 3] / sx;   // xmax
            v = (e == 0) ? b1 : (e == 1) ? b0 : (e == 2) ? b3 : b2;
        }
        out[1600 + p] = v;
    }
    // mask: [1700 .. 1724]
    if (tid < K) out[1700 + tid] = fgL[ordL[tid]] ? 1.0f : 0.0f;
}

extern "C" void kernel_launch(void* const* d_in, const int* in_sizes, int n_in,
                              void* d_out, int out_size, void* d_ws, size_t ws_size,
                              hipStream_t stream) {
    const float* roi_boxes  = (const float*)d_in[0];
    const float* roi_scores = (const float*)d_in[1];
    const float* det_boxes  = (const float*)d_in[2];
    // d_in[3] detection_masks: unused by reference
    const float* vis        = (const float*)d_in[4];
    const float* info       = (const float*)d_in[5];
    const float* tf         = (const float*)d_in[6];

    char* ws = (char*)d_ws;
    unsigned long long* keys = (unsigned long long*)(ws + 0);
    unsigned int* rank       = (unsigned int*)(ws + 131072);
    unsigned int* sidx       = (unsigned int*)(ws + 196608);
    float4* sbox             = (float4*)(ws + 262144);
    float* sarea             = (float*)(ws + 524288);
    unsigned long long* mask = (unsigned long long*)(ws + 589824);
    int* idxArr              = (int*)(ws + 34144256);
    unsigned char* keepOrig  = (unsigned char*)(ws + 34144384);

    k_build<<<64, 256, 0, stream>>>(roi_scores, keys, rank);
    k_rank<<<dim3(64, 8), 256, 0, stream>>>(keys, rank);
    k_scatter<<<64, 256, 0, stream>>>(rank, sidx);
    k_gather<<<64, 256, 0, stream>>>(sidx, det_boxes, sbox, sarea);
    k_mask<<<dim3(NWORDS, NWORDS), 64, 0, stream>>>(sbox, sarea, mask);
    k_scan<<<1, 64, 0, stream>>>(mask, sidx, keepOrig);
    k_select<<<1, 1024, 0, stream>>>(keepOrig, roi_boxes, roi_scores, det_boxes, info, idxArr);
    k_classify<<<1, 256, 0, stream>>>(vis, tf, det_boxes, info, idxArr, (float*)d_out);
}